// Round 18
// baseline (93.682 us; speedup 1.0000x reference)
//
#include <hip/hip_runtime.h>
#include <math.h>

#define NB 16
#define NE 5
#define LL 128
#define HH 768
#define NK 21
#define NCLS 3
#define NN (NB*NE)   // 80

typedef float f32x4 __attribute__((ext_vector_type(4)));
typedef float f32x8 __attribute__((ext_vector_type(8)));
typedef short s16x8 __attribute__((ext_vector_type(8)));

__device__ __forceinline__ short bf16rne(float f) {
    union { float f; unsigned u; } c; c.f = f;
    unsigned u = c.u;
    unsigned r = (u + 0x7FFFu + ((u >> 16) & 1u)) >> 16;
    return (short)r;
}
__device__ __forceinline__ float sum8(f32x8 x) {
    return ((x[0] + x[1]) + (x[2] + x[3])) + ((x[4] + x[5]) + (x[6] + x[7]));
}
__device__ __forceinline__ f32x8 exp2v(f32x8 x) {
    f32x8 r;
    r[0] = exp2f(x[0]); r[1] = exp2f(x[1]); r[2] = exp2f(x[2]); r[3] = exp2f(x[3]);
    r[4] = exp2f(x[4]); r[5] = exp2f(x[5]); r[6] = exp2f(x[6]); r[7] = exp2f(x[7]);
    return r;
}
__device__ __forceinline__ f32x8 mk8(float4 a, float4 b) {
    f32x8 r;
    r[0] = a.x; r[1] = a.y; r[2] = a.z; r[3] = a.w;
    r[4] = b.x; r[5] = b.y; r[6] = b.z; r[7] = b.w;
    return r;
}
__device__ __forceinline__ float dot4(float4 a, float4 b) {
    return fmaf(a.x, b.x, fmaf(a.y, b.y, fmaf(a.z, b.z, a.w * b.w)));
}

// ------- K0: prep (blocks 0..639) + W1 transpose (blocks 640..687) -----------
__global__ __launch_bounds__(256) void k_prep(const float* __restrict__ hid,
                                              short* __restrict__ hswz,
                                              const float* __restrict__ W1,
                                              float* __restrict__ w1t) {
    __shared__ float sT[64][65];
    const int tid = threadIdx.x;
    if (blockIdx.x >= 640) {
        const int bb = blockIdx.x - 640;
        const int tI = bb >> 1, jI = bb & 1;
        #pragma unroll
        for (int i = 0; i < 16; ++i) {
            const int r = (tid >> 6) + i * 4, c = tid & 63;
            sT[r][c] = W1[(size_t)(tI * 64 + r) * 128 + jI * 64 + c];
        }
        __syncthreads();
        #pragma unroll
        for (int i = 0; i < 16; ++i) {
            const int r = (tid >> 6) + i * 4, c = tid & 63;
            w1t[(size_t)(jI * 64 + r) * 1536 + tI * 64 + c] = sT[c][r];
        }
        return;
    }
    const int n = blockIdx.x >> 3, slab = blockIdx.x & 7;
    const int l = tid & 63, w = tid >> 6;
    float* sInv = &sT[0][0];
    #pragma unroll
    for (int rr = 0; rr < 4; ++rr) {
        const int lr = w * 4 + rr;
        const int row = slab * 16 + lr;
        const float4* rp = reinterpret_cast<const float4*>(hid + ((size_t)n * LL + row) * HH);
        float4 a = rp[l], b = rp[l + 64], c = rp[l + 128];
        float ss = a.x*a.x + a.y*a.y + a.z*a.z + a.w*a.w
                 + b.x*b.x + b.y*b.y + b.z*b.z + b.w*b.w
                 + c.x*c.x + c.y*c.y + c.z*c.z + c.w*c.w;
        #pragma unroll
        for (int o = 32; o > 0; o >>= 1) ss += __shfl_xor(ss, o, 64);
        if (l == 0) sInv[lr] = 1.0f / fmaxf(sqrtf(ss), 1e-12f);
    }
    __syncthreads();
    const float* base = hid + (size_t)n * LL * HH;
    s16x8* dst = reinterpret_cast<s16x8*>(hswz) + (size_t)n * 12288;
    #pragma unroll
    for (int i = 0; i < 6; ++i) {
        const int uid = i * 256 + tid;          // 0..1535
        const int s = uid >> 6, sub = uid & 63;
        const int r15 = sub >> 2, kc = sub & 3;
        const int row = slab * 16 + r15;
        const int k0 = s * 32 + kc * 8;
        const float4* p = reinterpret_cast<const float4*>(base + (size_t)row * HH + k0);
        float4 v0 = p[0], v1 = p[1];
        const float inv = sInv[r15];
        s16x8 h;
        h[0] = bf16rne(v0.x * inv); h[1] = bf16rne(v0.y * inv);
        h[2] = bf16rne(v0.z * inv); h[3] = bf16rne(v0.w * inv);
        h[4] = bf16rne(v1.x * inv); h[5] = bf16rne(v1.y * inv);
        h[6] = bf16rne(v1.z * inv); h[7] = bf16rne(v1.w * inv);
        dst[(size_t)s * 512 + slab * 64 + kc * 16 + r15] = h;
    }
}

// ------- K2: MFMA sim, 128x128 tile, 512 threads / 8 waves (grid 400) --------
// wave w: rw = w&3 (rows rw*32..+32), cw = w>>2 (cols cw*64..+64).
__global__ __launch_bounds__(512, 2) void k_simpool(
    const short* __restrict__ hswz,
    const float* __restrict__ mask_text, const float* __restrict__ mask_claim,
    const float* __restrict__ mask_evidence,
    const float* __restrict__ W_att, const float* __restrict__ b_att,
    const float* __restrict__ W_sel,
    float* __restrict__ attw, float2* __restrict__ dselPart)
{
    const int bid = blockIdx.x;                 // 0..399
    const int b = bid & 15, pair = bid >> 4;    // pair 0..24
    const int e = pair / NE, ep = pair - e * NE;
    const int nq = b * NE + e, nd = b * NE + ep;
    const bool diag = (e == ep);
    const int tid = threadIdx.x, lane = tid & 63, w = tid >> 6;  // w: 0..7
    const int lx = lane & 15, lg = lane >> 4;
    const int rw = w & 3, cw = w >> 2;          // row group (32), col half (64)

    __shared__ s16x8 sB[2][1024];               // 32 KB dbuf; reused as half sim tile
    __shared__ __align__(16) float sMT[LL];
    __shared__ __align__(16) float sMEd[LL];
    __shared__ float sMEq[LL], sMCq[LL], sSel[64];
    __shared__ float sWA[NK], sWS[NK], sCK[NK];

    if (tid < 128) {
        sMT[tid]  = mask_text[nd * LL + tid];
        sMEd[tid] = mask_evidence[nd * LL + tid];
    } else if (tid < 256) {
        const int q = tid - 128;
        sMEq[q] = mask_evidence[nq * LL + q];
        sMCq[q] = mask_claim[nq * LL + q];
    } else if (tid < 256 + NK) {
        sWA[tid - 256] = W_att[tid - 256] * 0.69314718f;
    } else if (tid >= 288 && tid < 288 + NK) {
        sWS[tid - 288] = W_sel[tid - 288] * 0.69314718f;
    } else if (tid >= 320 && tid < 340) {
        const int k = tid - 319;                // 1..20
        const float kk = (float)(k - 1);
        sCK[k] = exp2f(fmaf(kk, 13.7056029f, fmaf(kk * kk, -0.72134752f, -32.0f)));
    } else if (tid == 340) {
        sCK[0] = 1.0f;
    }

    const s16x8* gA = reinterpret_cast<const s16x8*>(hswz) + (size_t)nq * 12288;
    const s16x8* gB = reinterpret_cast<const s16x8*>(hswz) + (size_t)nd * 12288;

    // A unit bases: wave's two 16-row tiles
    const int rt0 = (rw * 2) * 64;
    const int rt1 = rt0 + 64;

    // prologue: stage B(0) (2 units/thread); load A(0) frags (4)
    {
        s16x8 t0 = gB[tid], t1 = gB[tid + 512];
        sB[0][tid] = t0; sB[0][tid + 512] = t1;
    }
    s16x8 a00 = gA[rt0 + lane], a01 = gA[512 + rt0 + lane];
    s16x8 a10 = gA[rt1 + lane], a11 = gA[512 + rt1 + lane];

    f32x4 acc[2][4];                            // [mi][j]
    #pragma unroll
    for (int mi = 0; mi < 2; ++mi)
        #pragma unroll
        for (int j = 0; j < 4; ++j) acc[mi][j] = (f32x4){0.f, 0.f, 0.f, 0.f};

    __syncthreads();

    const int cb = cw * 256;
    for (int s = 0; s < 12; ++s) {
        const int cur = s & 1;
        s16x8 nB0, nB1, n00, n01, n10, n11;
        if (s < 11) {
            const s16x8* gBs = gB + (s + 1) * 1024;
            nB0 = gBs[tid]; nB1 = gBs[tid + 512];
            const s16x8* gAs = gA + (s + 1) * 1024;
            n00 = gAs[rt0 + lane]; n01 = gAs[512 + rt0 + lane];
            n10 = gAs[rt1 + lane]; n11 = gAs[512 + rt1 + lane];
        }
        #pragma unroll
        for (int j = 0; j < 4; ++j) {
            s16x8 bf = sB[cur][cb + j * 64 + lane];
            acc[0][j] = __builtin_amdgcn_mfma_f32_16x16x32_bf16(a00, bf, acc[0][j], 0, 0, 0);
            acc[1][j] = __builtin_amdgcn_mfma_f32_16x16x32_bf16(a10, bf, acc[1][j], 0, 0, 0);
        }
        #pragma unroll
        for (int j = 0; j < 4; ++j) {
            s16x8 bf = sB[cur][512 + cb + j * 64 + lane];
            acc[0][j] = __builtin_amdgcn_mfma_f32_16x16x32_bf16(a01, bf, acc[0][j], 0, 0, 0);
            acc[1][j] = __builtin_amdgcn_mfma_f32_16x16x32_bf16(a11, bf, acc[1][j], 0, 0, 0);
        }
        if (s < 11) {
            sB[1 - cur][tid] = nB0; sB[1 - cur][tid + 512] = nB1;
            a00 = n00; a01 = n01; a10 = n10; a11 = n11;
            __syncthreads();
        }
    }

    // ---- 2-phase epilogue: half ph = rows ph*64..ph*64+64 ----
    float* sS = reinterpret_cast<float*>(sB);   // [64][128] swizzled
    const float bAtt = b_att[0];
    const size_t obase = ((size_t)ep * NN + nq) * LL;
    const int rloc = w * 8 + (lane >> 3);       // chain row within half 0..63
    const int sl   = lane & 7;                  // j-slice (16 cols)
    const int rx   = rloc & 31;

    #pragma unroll
    for (int ph = 0; ph < 2; ++ph) {
        __syncthreads();                        // prior users of sS/sB/sSel done
        if ((rw >> 1) == ph) {
            #pragma unroll
            for (int mi = 0; mi < 2; ++mi) {
                #pragma unroll
                for (int j = 0; j < 4; ++j) {
                    const int col = cw * 64 + j * 16 + lx;
                    const int uu = col >> 2, ce = col & 3;
                    #pragma unroll
                    for (int r = 0; r < 4; ++r) {
                        const int rl = (rw & 1) * 32 + mi * 16 + lg * 4 + r;
                        sS[rl * 128 + ((uu ^ (rl & 31)) << 2) + ce] = acc[mi][j][r];
                    }
                }
            }
        }
        __syncthreads();

        const int grow = ph * 64 + rloc;        // global q row
        const float4* rp4 = reinterpret_cast<const float4*>(sS + rloc * 128);

        float pk[NK], vk[NK];
        #pragma unroll
        for (int k = 0; k < NK; ++k) { pk[k] = 0.f; vk[k] = 0.f; }

        #pragma unroll
        for (int c = 0; c < 2; ++c) {
            const float4 va = rp4[(sl * 4 + c * 2) ^ rx];
            const float4 vb = rp4[(sl * 4 + c * 2 + 1) ^ rx];
            const f32x8 s = mk8(va, vb);
            const int j0 = sl * 16 + c * 8;
            const f32x8 m = mk8(*reinterpret_cast<const float4*>(&sMT[j0]),
                                *reinterpret_cast<const float4*>(&sMT[j0 + 4]));
            f32x8 d = s - 1.0f;
            const f32x8 g = exp2v(d * d * -721347.52f);
            pk[0] += sum8(m * g);
            const f32x8 t = exp2v(s * -14.4269504f);
            d = s - 0.95f;
            const f32x8 P = exp2v(d * d * -72.134752f + 32.0f);
            f32x8 u = m * P;
            pk[1] += sum8(u);
            #pragma unroll
            for (int k = 2; k <= 20; ++k) { u *= t; pk[k] += sum8(u); }
            if (diag) {
                const f32x8 me = mk8(*reinterpret_cast<const float4*>(&sMEd[j0]),
                                     *reinterpret_cast<const float4*>(&sMEd[j0 + 4]));
                f32x8 uv = me * P;
                vk[0] += sum8(me * g);
                vk[1] += sum8(uv);
                #pragma unroll
                for (int k = 2; k <= 20; ++k) { uv *= t; vk[k] += sum8(uv); }
            }
        }
        #pragma unroll
        for (int k = 0; k < NK; ++k) {
            pk[k] += __shfl_xor(pk[k], 1, 64);
            pk[k] += __shfl_xor(pk[k], 2, 64);
            pk[k] += __shfl_xor(pk[k], 4, 64);
        }
        if (diag) {
            #pragma unroll
            for (int k = 0; k < NK; ++k) {
                vk[k] += __shfl_xor(vk[k], 1, 64);
                vk[k] += __shfl_xor(vk[k], 2, 64);
                vk[k] += __shfl_xor(vk[k], 4, 64);
            }
        }
        float lgt = bAtt;
        #pragma unroll
        for (int k = 0; k < NK; ++k)
            lgt = fmaf(sWA[k], log2f(fmaxf(pk[k] * sCK[k], 1e-10f)), lgt);
        if (sl == 0)
            attw[obase + grow] = (sMEq[grow] == 0.0f) ? -10000.0f : lgt;
        if (diag) {
            float rv = 0.f;
            #pragma unroll
            for (int k = 0; k < NK; ++k)
                rv = fmaf(sWS[k], log2f(fmaxf(vk[k] * sCK[k], 1e-10f)), rv);
            if (sl == 0) sSel[rloc] = sMCq[grow] * rv;
            __syncthreads();
            if (tid < 64) {
                float su = sSel[tid], ms = sMCq[ph * 64 + tid];
                #pragma unroll
                for (int o = 32; o > 0; o >>= 1) {
                    su += __shfl_xor(su, o, 64);
                    ms += __shfl_xor(ms, o, 64);
                }
                if (tid == 0) dselPart[nq * 2 + ph] = make_float2(su, ms);
            }
        }
    }
}

// ------- K3: softmax over q + denoise (float4-across-h, q-split-4) -----------
__global__ __launch_bounds__(256) void k_denoise(
    const float* __restrict__ hid, const float* __restrict__ attw,
    float* __restrict__ denoi)
{
    const int blk = blockIdx.x;          // nq*3 + chunk
    const int nq = blk / 3, ch = blk - nq * 3;
    const int tid = threadIdx.x, l = tid & 63, g = tid >> 6;
    __shared__ float sA[NE][LL];
    __shared__ f32x4 sP[4][NE][64];      // 20 KB partials
    for (int ep = g; ep < NE; ep += 4) {
        const float* ap = attw + ((size_t)ep * NN + nq) * LL;
        float a0 = ap[l], a1 = ap[l + 64];
        float m = fmaxf(a0, a1);
        #pragma unroll
        for (int o = 32; o > 0; o >>= 1) m = fmaxf(m, __shfl_xor(m, o, 64));
        float e0 = __expf(a0 - m), e1 = __expf(a1 - m);
        float s = e0 + e1;
        #pragma unroll
        for (int o = 32; o > 0; o >>= 1) s += __shfl_xor(s, o, 64);
        float inv = 1.0f / s;
        sA[ep][l] = e0 * inv;
        sA[ep][l + 64] = e1 * inv;
    }
    __syncthreads();
    const int h = ch * 256 + l * 4;
    const f32x4* hp = reinterpret_cast<const f32x4*>(hid + (size_t)nq * LL * HH + h);
    f32x4 p0 = {0,0,0,0}, p1 = {0,0,0,0}, p2 = {0,0,0,0}, p3 = {0,0,0,0}, p4 = {0,0,0,0};
    #pragma unroll 8
    for (int q = 0; q < 32; ++q) {
        const int qq = g * 32 + q;
        const f32x4 x = hp[(size_t)qq * (HH / 4)];
        p0 += sA[0][qq] * x;
        p1 += sA[1][qq] * x;
        p2 += sA[2][qq] * x;
        p3 += sA[3][qq] * x;
        p4 += sA[4][qq] * x;
    }
    sP[g][0][l] = p0; sP[g][1][l] = p1; sP[g][2][l] = p2;
    sP[g][3][l] = p3; sP[g][4][l] = p4;
    __syncthreads();
    if (tid < 64) {
        #define DNST(EP) { \
            f32x4 r = sP[0][EP][l] + sP[1][EP][l] + sP[2][EP][l] + sP[3][EP][l]; \
            *reinterpret_cast<f32x4*>(denoi + ((size_t)(EP) * NN + nq) * HH + h) = r; }
        DNST(0) DNST(1) DNST(2) DNST(3) DNST(4)
        #undef DNST
    }
}

// ---- K5b: GAT gate — float4, fully unrolled, one wave per (j-pair, 8 p's) ---
__global__ __launch_bounds__(256) void k_gat2(
    const float* __restrict__ inputs, const float* __restrict__ denoise,
    const float* __restrict__ w1t, const float* __restrict__ b1,
    const float* __restrict__ W2, float* __restrict__ part)
{
    const int wid = blockIdx.x * 4 + (threadIdx.x >> 6);
    const int l = threadIdx.x & 63;
    const int jp = wid & 63;
    const int po = wid >> 6;
    const int j0 = jp * 2, j1 = j0 + 1;
    const int pb = po * 8;

    const float4* wc0 = reinterpret_cast<const float4*>(w1t + (size_t)j0 * 1536) + l;
    const float4* wc1 = reinterpret_cast<const float4*>(w1t + (size_t)j1 * 1536) + l;
    const float4* fin[8]; const float4* fde[8];
    #pragma unroll
    for (int u = 0; u < 8; ++u) {
        const int p = pb + u;
        const int i = p / NN; const int n2 = p - i * NN; const int bb = n2 / NE;
        fin[u] = reinterpret_cast<const float4*>(inputs + ((size_t)bb * NE + i) * HH) + l;
        fde[u] = reinterpret_cast<const float4*>(denoise + (size_t)p * HH) + l;
    }
    float a0[8], a1[8];
    #pragma unroll
    for (int u = 0; u < 8; ++u) { a0[u] = 0.f; a1[u] = 0.f; }

    #pragma unroll
    for (int it = 0; it < 3; ++it) {
        const float4 w0v = wc0[it * 64], w1v = wc1[it * 64];
        #pragma unroll
        for (int u = 0; u < 8; ++u) {
            const float4 f = fin[u][it * 64];
            a0[u] += dot4(f, w0v);
            a1[u] += dot4(f, w1v);
        }
    }
    #pragma unroll
    for (int it = 0; it < 3; ++it) {
        const float4 w0v = wc0[192 + it * 64], w1v = wc1[192 + it * 64];
        #pragma unroll
        for (int u = 0; u < 8; ++u) {
            const float4 f = fde[u][it * 64];
            a0[u] += dot4(f, w0v);
            a1[u] += dot4(f, w1v);
        }
    }
    #pragma unroll
    for (int u = 0; u < 8; ++u) {
        #pragma unroll
        for (int o = 32; o > 0; o >>= 1) {
            a0[u] += __shfl_xor(a0[u], o, 64);
            a1[u] += __shfl_xor(a1[u], o, 64);
        }
    }
    const float bb0 = b1[j0], bb1 = b1[j1], w20 = W2[j0], w21 = W2[j1];
    if (l == 0) {
        #pragma unroll
        for (int u = 0; u < 8; ++u) {
            float v = fmaxf(a0[u] + bb0, 0.f) * w20 + fmaxf(a1[u] + bb1, 0.f) * w21;
            part[(size_t)(pb + u) * 64 + jp] = v;
        }
    }
}

// ---------------- K6a: per-(b,i) class logits (inlines gsc reduce) ----------
__global__ __launch_bounds__(256) void k_logits(
    const float* __restrict__ inputs, const float* __restrict__ denoise,
    const float* __restrict__ part, const float* __restrict__ inf_W,
    const float* __restrict__ inf_b, float* __restrict__ logi)
{
    const int bid = blockIdx.x;        // b*NE + i
    const int b = bid / NE, i = bid - b * NE;
    const int tid = threadIdx.x, l = tid & 63, wv = tid >> 6;
    __shared__ float sG[NE];
    for (int e2 = wv; e2 < NE; e2 += 4) {
        float v = part[(size_t)(i * NN + b * NE + e2) * 64 + l];
        #pragma unroll
        for (int o = 32; o > 0; o >>= 1) v += __shfl_xor(v, o, 64);
        if (l == 0) sG[e2] = v;
    }
    __syncthreads();
    float g0 = sG[0], g1 = sG[1], g2 = sG[2], g3 = sG[3], g4 = sG[4];
    float mm = fmaxf(fmaxf(fmaxf(g0, g1), fmaxf(g2, g3)), g4);
    float w0 = __expf(g0 - mm), w1 = __expf(g1 - mm), w2 = __expf(g2 - mm);
    float w3 = __expf(g3 - mm), w4 = __expf(g4 - mm);
    float inv = 1.0f / (w0 + w1 + w2 + w3 + w4);
    w0 *= inv; w1 *= inv; w2 *= inv; w3 *= inv; w4 *= inv;

    float p0 = 0.f, p1 = 0.f, p2 = 0.f;
    const float* xin = inputs + ((size_t)b * NE + i) * HH;
    const float* de = denoise + ((size_t)i * NN + b * NE) * HH;
    #pragma unroll
    for (int it = 0; it < 3; ++it) {
        int t = it * 256 + tid;
        float f = xin[t];
        p0 += f * inf_W[t * 3]; p1 += f * inf_W[t * 3 + 1]; p2 += f * inf_W[t * 3 + 2];
    }
    #pragma unroll
    for (int it = 0; it < 3; ++it) {
        int h = it * 256 + tid;
        float a = w0 * de[h] + w1 * de[HH + h] + w2 * de[2 * HH + h]
                + w3 * de[3 * HH + h] + w4 * de[4 * HH + h];
        int t = HH + h;
        p0 += a * inf_W[t * 3]; p1 += a * inf_W[t * 3 + 1]; p2 += a * inf_W[t * 3 + 2];
    }
    #pragma unroll
    for (int o = 32; o > 0; o >>= 1) {
        p0 += __shfl_xor(p0, o, 64);
        p1 += __shfl_xor(p1, o, 64);
        p2 += __shfl_xor(p2, o, 64);
    }
    __shared__ float red[4][NCLS];
    if (l == 0) { red[wv][0] = p0; red[wv][1] = p1; red[wv][2] = p2; }
    __syncthreads();
    if (tid < NCLS) {
        logi[bid * NCLS + tid] = red[0][tid] + red[1][tid] + red[2][tid] + red[3][tid]
                               + inf_b[tid];
    }
}

// ---------------- K6b: combine (finalizes dsel from partials) ---------------
__global__ __launch_bounds__(64) void k_combine(
    const float2* __restrict__ dselPart, const float* __restrict__ b_sel,
    const float* __restrict__ logi, float* __restrict__ out)
{
    const int b = threadIdx.x;
    if (b >= NB) return;
    const float bs = b_sel[0];
    float d0, d1, d2, d3, d4;
#define DSEL(I, D) { float2 pa = dselPart[(b * NE + (I)) * 2], pb = dselPart[(b * NE + (I)) * 2 + 1]; \
                     (D) = bs + 0.01f * (pa.x + pb.x) / ((pa.y + pb.y) + 1e-10f); }
    DSEL(0, d0) DSEL(1, d1) DSEL(2, d2) DSEL(3, d3) DSEL(4, d4)
#undef DSEL
    float m = fmaxf(fmaxf(fmaxf(d0, d1), fmaxf(d2, d3)), d4);
    float s0 = __expf(d0 - m), s1 = __expf(d1 - m), s2 = __expf(d2 - m);
    float s3 = __expf(d3 - m), s4 = __expf(d4 - m);
    float sinv = 1.0f / (s0 + s1 + s2 + s3 + s4);
    float sp0 = s0 * sinv, sp1 = s1 * sinv, sp2 = s2 * sinv, sp3 = s3 * sinv, sp4 = s4 * sinv;
    float acc0 = 0.f, acc1 = 0.f, acc2 = 0.f;
#define CMB(I, SP) { \
        float l0 = logi[(b * NE + (I)) * NCLS], l1 = logi[(b * NE + (I)) * NCLS + 1], \
              l2 = logi[(b * NE + (I)) * NCLS + 2]; \
        float mm = fmaxf(fmaxf(l0, l1), l2); \
        float e0 = __expf(l0 - mm), e1 = __expf(l1 - mm), e2 = __expf(l2 - mm); \
        float si = 1.0f / (e0 + e1 + e2); \
        acc0 += (SP) * e0 * si; acc1 += (SP) * e1 * si; acc2 += (SP) * e2 * si; }
    CMB(0, sp0) CMB(1, sp1) CMB(2, sp2) CMB(3, sp3) CMB(4, sp4)
#undef CMB
    out[b * NCLS + 0] = logf(acc0);
    out[b * NCLS + 1] = logf(acc1);
    out[b * NCLS + 2] = logf(acc2);
}

extern "C" void kernel_launch(void* const* d_in, const int* in_sizes, int n_in,
                              void* d_out, int out_size, void* d_ws, size_t ws_size,
                              hipStream_t stream) {
    (void)in_sizes; (void)n_in; (void)out_size; (void)ws_size;
    const float* hid           = (const float*)d_in[0];
    const float* inputs        = (const float*)d_in[1];
    const float* mask_text     = (const float*)d_in[2];
    const float* mask_claim    = (const float*)d_in[3];
    const float* mask_evidence = (const float*)d_in[4];
    const float* W_att  = (const float*)d_in[5];
    const float* b_att  = (const float*)d_in[6];
    const float* W_sel  = (const float*)d_in[7];
    const float* b_sel  = (const float*)d_in[8];
    const float* gat_W1 = (const float*)d_in[9];
    const float* gat_b1 = (const float*)d_in[10];
    const float* gat_W2 = (const float*)d_in[11];
    const float* gat_b2 = (const float*)d_in[12];
    const float* inf_W  = (const float*)d_in[13];
    const float* inf_b  = (const float*)d_in[14];
    (void)gat_b2;

    short* hswz  = (short*)d_ws;                              // 15,728,640 B
    float* denoi = (float*)((char*)d_ws + 15728640);          // 307,200 f
    float* attw  = denoi + 307200;                            // 51,200 f
    float2* dselPart = (float2*)(attw + 51200);               // 160 float2
    float* w1t   = (float*)(dselPart + 160);                  // 196,608 f
    float* part  = w1t + 196608;                              // 25,600 f
    float* logi  = part + 25600;                              // 240 f

    k_prep<<<688, 256, 0, stream>>>(hid, hswz, gat_W1, w1t);
    k_simpool<<<400, 512, 0, stream>>>(hswz, mask_text, mask_claim, mask_evidence,
                                       W_att, b_att, W_sel, attw, dselPart);
    k_denoise<<<NN * 3, 256, 0, stream>>>(hid, attw, denoi);
    k_gat2<<<800, 256, 0, stream>>>(inputs, denoi, w1t, gat_b1, gat_W2, part);
    k_logits<<<NN, 256, 0, stream>>>(inputs, denoi, part, inf_W, inf_b, logi);
    k_combine<<<1, 64, 0, stream>>>(dselPart, b_sel, logi, (float*)d_out);
}

// Round 19
// 81.486 us; speedup vs baseline: 1.1497x; 1.1497x over previous
//
#include <hip/hip_runtime.h>
#include <math.h>

#define NB 16
#define NE 5
#define LL 128
#define HH 768
#define NK 21
#define NCLS 3
#define NN (NB*NE)   // 80

typedef float f32x4 __attribute__((ext_vector_type(4)));
typedef float f32x8 __attribute__((ext_vector_type(8)));
typedef short s16x8 __attribute__((ext_vector_type(8)));

__device__ __forceinline__ short bf16rne(float f) {
    union { float f; unsigned u; } c; c.f = f;
    unsigned u = c.u;
    unsigned r = (u + 0x7FFFu + ((u >> 16) & 1u)) >> 16;
    return (short)r;
}
__device__ __forceinline__ float sum8(f32x8 x) {
    return ((x[0] + x[1]) + (x[2] + x[3])) + ((x[4] + x[5]) + (x[6] + x[7]));
}
__device__ __forceinline__ f32x8 exp2v(f32x8 x) {
    f32x8 r;
    r[0] = exp2f(x[0]); r[1] = exp2f(x[1]); r[2] = exp2f(x[2]); r[3] = exp2f(x[3]);
    r[4] = exp2f(x[4]); r[5] = exp2f(x[5]); r[6] = exp2f(x[6]); r[7] = exp2f(x[7]);
    return r;
}
__device__ __forceinline__ f32x8 mk8(float4 a, float4 b) {
    f32x8 r;
    r[0] = a.x; r[1] = a.y; r[2] = a.z; r[3] = a.w;
    r[4] = b.x; r[5] = b.y; r[6] = b.z; r[7] = b.w;
    return r;
}
__device__ __forceinline__ float dot4(float4 a, float4 b) {
    return fmaf(a.x, b.x, fmaf(a.y, b.y, fmaf(a.z, b.z, a.w * b.w)));
}

// ------- K0: prep (blocks 0..639) + W1 transpose (blocks 640..687) -----------
__global__ __launch_bounds__(256) void k_prep(const float* __restrict__ hid,
                                              short* __restrict__ hswz,
                                              const float* __restrict__ W1,
                                              float* __restrict__ w1t) {
    __shared__ float sT[64][65];
    const int tid = threadIdx.x;
    if (blockIdx.x >= 640) {
        const int bb = blockIdx.x - 640;
        const int tI = bb >> 1, jI = bb & 1;
        #pragma unroll
        for (int i = 0; i < 16; ++i) {
            const int r = (tid >> 6) + i * 4, c = tid & 63;
            sT[r][c] = W1[(size_t)(tI * 64 + r) * 128 + jI * 64 + c];
        }
        __syncthreads();
        #pragma unroll
        for (int i = 0; i < 16; ++i) {
            const int r = (tid >> 6) + i * 4, c = tid & 63;
            w1t[(size_t)(jI * 64 + r) * 1536 + tI * 64 + c] = sT[c][r];
        }
        return;
    }
    const int n = blockIdx.x >> 3, slab = blockIdx.x & 7;
    const int l = tid & 63, w = tid >> 6;
    float* sInv = &sT[0][0];
    #pragma unroll
    for (int rr = 0; rr < 4; ++rr) {
        const int lr = w * 4 + rr;
        const int row = slab * 16 + lr;
        const float4* rp = reinterpret_cast<const float4*>(hid + ((size_t)n * LL + row) * HH);
        float4 a = rp[l], b = rp[l + 64], c = rp[l + 128];
        float ss = a.x*a.x + a.y*a.y + a.z*a.z + a.w*a.w
                 + b.x*b.x + b.y*b.y + b.z*b.z + b.w*b.w
                 + c.x*c.x + c.y*c.y + c.z*c.z + c.w*c.w;
        #pragma unroll
        for (int o = 32; o > 0; o >>= 1) ss += __shfl_xor(ss, o, 64);
        if (l == 0) sInv[lr] = 1.0f / fmaxf(sqrtf(ss), 1e-12f);
    }
    __syncthreads();
    const float* base = hid + (size_t)n * LL * HH;
    s16x8* dst = reinterpret_cast<s16x8*>(hswz) + (size_t)n * 12288;
    #pragma unroll
    for (int i = 0; i < 6; ++i) {
        const int uid = i * 256 + tid;          // 0..1535
        const int s = uid >> 6, sub = uid & 63;
        const int r15 = sub >> 2, kc = sub & 3;
        const int row = slab * 16 + r15;
        const int k0 = s * 32 + kc * 8;
        const float4* p = reinterpret_cast<const float4*>(base + (size_t)row * HH + k0);
        float4 v0 = p[0], v1 = p[1];
        const float inv = sInv[r15];
        s16x8 h;
        h[0] = bf16rne(v0.x * inv); h[1] = bf16rne(v0.y * inv);
        h[2] = bf16rne(v0.z * inv); h[3] = bf16rne(v0.w * inv);
        h[4] = bf16rne(v1.x * inv); h[5] = bf16rne(v1.y * inv);
        h[6] = bf16rne(v1.z * inv); h[7] = bf16rne(v1.w * inv);
        dst[(size_t)s * 512 + slab * 64 + kc * 16 + r15] = h;
    }
}

// ------- K2: MFMA sim (BK=64, dbuf, 2x4 wave tiling) + pooled logits ---------
// grid 800: bid = b + 16*(pair*2 + qh); wave w: rows (w&1)*32..+32, cols (w>>1)*64..+64.
__global__ __launch_bounds__(256, 2) void k_simpool(
    const short* __restrict__ hswz,
    const float* __restrict__ mask_text, const float* __restrict__ mask_claim,
    const float* __restrict__ mask_evidence,
    const float* __restrict__ W_att, const float* __restrict__ b_att,
    const float* __restrict__ W_sel,
    float* __restrict__ attw, float2* __restrict__ dselPart)
{
    const int bid = blockIdx.x;
    const int b = bid & 15, rest = bid >> 4;    // 0..49
    const int pair = rest >> 1, qh = rest & 1;
    const int e = pair / NE, ep = pair - e * NE;
    const int nq = b * NE + e, nd = b * NE + ep;
    const bool diag = (e == ep);
    const int tid = threadIdx.x, lane = tid & 63, w = tid >> 6;  // w: 0..3
    const int lx = lane & 15, lg = lane >> 4;
    const int rw = w & 1, cw = w >> 1;          // row-pair, col-half

    __shared__ s16x8 sB[2][1024];               // 32 KB dbuf; reused as sim tile
    __shared__ __align__(16) float sMT[LL];
    __shared__ __align__(16) float sMEd[LL];
    __shared__ float sMEq[64], sMCq[64], sSel[64];
    __shared__ float sWA[NK], sWS[NK], sCK[NK];

    if (tid < 128) {
        sMT[tid]  = mask_text[nd * LL + tid];
        sMEd[tid] = mask_evidence[nd * LL + tid];
    } else if (tid < 192) {
        const int q = tid - 128;
        sMEq[q] = mask_evidence[nq * LL + qh * 64 + q];
        sMCq[q] = mask_claim[nq * LL + qh * 64 + q];
    } else if (tid < 192 + NK) {
        sWA[tid - 192] = W_att[tid - 192] * 0.69314718f;
    } else if (tid < 213 + NK) {
        sWS[tid - 213] = W_sel[tid - 213] * 0.69314718f;
    } else if (tid < 254) {
        const int k = tid - 233;                // 1..20
        const float kk = (float)(k - 1);
        sCK[k] = exp2f(fmaf(kk, 13.7056029f, fmaf(kk * kk, -0.72134752f, -32.0f)));
    } else if (tid == 254) {
        sCK[0] = 1.0f;
    }

    const s16x8* gA = reinterpret_cast<const s16x8*>(hswz) + (size_t)nq * 12288;
    const s16x8* gB = reinterpret_cast<const s16x8*>(hswz) + (size_t)nd * 12288;

    const int rt0 = (qh * 4 + rw * 2) * 64;
    const int rt1 = rt0 + 64;

    {
        s16x8 t0 = gB[tid], t1 = gB[tid + 256], t2 = gB[tid + 512], t3 = gB[tid + 768];
        sB[0][tid] = t0; sB[0][tid + 256] = t1;
        sB[0][tid + 512] = t2; sB[0][tid + 768] = t3;
    }
    s16x8 a00 = gA[rt0 + lane],       a01 = gA[512 + rt0 + lane];
    s16x8 a10 = gA[rt1 + lane],       a11 = gA[512 + rt1 + lane];

    f32x4 acc[2][4];
    #pragma unroll
    for (int mi = 0; mi < 2; ++mi)
        #pragma unroll
        for (int j = 0; j < 4; ++j) acc[mi][j] = (f32x4){0.f, 0.f, 0.f, 0.f};

    __syncthreads();

    const int cb = cw * 256;
    for (int s = 0; s < 12; ++s) {
        const int cur = s & 1;
        s16x8 nB0, nB1, nB2, nB3, n00, n01, n10, n11;
        if (s < 11) {
            const s16x8* gBs = gB + (s + 1) * 1024;
            nB0 = gBs[tid]; nB1 = gBs[tid + 256];
            nB2 = gBs[tid + 512]; nB3 = gBs[tid + 768];
            const s16x8* gAs = gA + (s + 1) * 1024;
            n00 = gAs[rt0 + lane]; n01 = gAs[512 + rt0 + lane];
            n10 = gAs[rt1 + lane]; n11 = gAs[512 + rt1 + lane];
        }
        #pragma unroll
        for (int j = 0; j < 4; ++j) {
            s16x8 b0 = sB[cur][cb + j * 64 + lane];
            acc[0][j] = __builtin_amdgcn_mfma_f32_16x16x32_bf16(a00, b0, acc[0][j], 0, 0, 0);
            acc[1][j] = __builtin_amdgcn_mfma_f32_16x16x32_bf16(a10, b0, acc[1][j], 0, 0, 0);
        }
        #pragma unroll
        for (int j = 0; j < 4; ++j) {
            s16x8 b1 = sB[cur][512 + cb + j * 64 + lane];
            acc[0][j] = __builtin_amdgcn_mfma_f32_16x16x32_bf16(a01, b1, acc[0][j], 0, 0, 0);
            acc[1][j] = __builtin_amdgcn_mfma_f32_16x16x32_bf16(a11, b1, acc[1][j], 0, 0, 0);
        }
        if (s < 11) {
            sB[1 - cur][tid] = nB0; sB[1 - cur][tid + 256] = nB1;
            sB[1 - cur][tid + 512] = nB2; sB[1 - cur][tid + 768] = nB3;
            a00 = n00; a01 = n01; a10 = n10; a11 = n11;
            __syncthreads();
        }
    }

    // ---- transpose sims into LDS (XOR-swizzled float4 units), reusing sB ----
    __syncthreads();
    float* sS = reinterpret_cast<float*>(sB);   // [64][128] swizzled
    {
        #pragma unroll
        for (int mi = 0; mi < 2; ++mi) {
            #pragma unroll
            for (int j = 0; j < 4; ++j) {
                const int col = cw * 64 + j * 16 + lx;
                const int uu = col >> 2, ce = col & 3;
                #pragma unroll
                for (int r = 0; r < 4; ++r) {
                    const int row = rw * 32 + mi * 16 + lg * 4 + r;
                    sS[row * 128 + ((uu ^ (row & 31)) << 2) + ce] = acc[mi][j][r];
                }
            }
        }
    }
    __syncthreads();

    // ---- per-thread chain: one row x 32 j's, all partials in registers ----
    const int row = w * 16 + (lane & 15);
    const int sl  = lane >> 4;
    const int rx  = row & 31;
    const float4* rp = reinterpret_cast<const float4*>(sS + row * 128);

    float pk[NK], vk[NK];
    #pragma unroll
    for (int k = 0; k < NK; ++k) { pk[k] = 0.f; vk[k] = 0.f; }

    #pragma unroll
    for (int c = 0; c < 4; ++c) {
        const float4 va = rp[(sl * 8 + c * 2) ^ rx];
        const float4 vb = rp[(sl * 8 + c * 2 + 1) ^ rx];
        const f32x8 s = mk8(va, vb);
        const int j0 = sl * 32 + c * 8;
        const f32x8 m = mk8(*reinterpret_cast<const float4*>(&sMT[j0]),
                            *reinterpret_cast<const float4*>(&sMT[j0 + 4]));
        f32x8 d = s - 1.0f;
        const f32x8 g = exp2v(d * d * -721347.52f);
        pk[0] += sum8(m * g);
        const f32x8 t = exp2v(s * -14.4269504f);
        d = s - 0.95f;
        const f32x8 P = exp2v(d * d * -72.134752f + 32.0f);
        f32x8 u = m * P;
        pk[1] += sum8(u);
        #pragma unroll
        for (int k = 2; k <= 20; ++k) { u *= t; pk[k] += sum8(u); }
        if (diag) {
            const f32x8 me = mk8(*reinterpret_cast<const float4*>(&sMEd[j0]),
                                 *reinterpret_cast<const float4*>(&sMEd[j0 + 4]));
            f32x8 uv = me * P;
            vk[0] += sum8(me * g);
            vk[1] += sum8(uv);
            #pragma unroll
            for (int k = 2; k <= 20; ++k) { uv *= t; vk[k] += sum8(uv); }
        }
    }
    #pragma unroll
    for (int k = 0; k < NK; ++k) {
        pk[k] += __shfl_xor(pk[k], 16, 64);
        pk[k] += __shfl_xor(pk[k], 32, 64);
    }
    if (diag) {
        #pragma unroll
        for (int k = 0; k < NK; ++k) {
            vk[k] += __shfl_xor(vk[k], 16, 64);
            vk[k] += __shfl_xor(vk[k], 32, 64);
        }
    }
    const float bAtt = b_att[0];
    float lgt = bAtt;
    #pragma unroll
    for (int k = 0; k < NK; ++k)
        lgt = fmaf(sWA[k], log2f(fmaxf(pk[k] * sCK[k], 1e-10f)), lgt);
    if (sl == 0) {
        const size_t obase = ((size_t)ep * NN + nq) * LL + qh * 64;
        attw[obase + row] = (sMEq[row] == 0.0f) ? -10000.0f : lgt;
    }
    if (diag) {
        float rv = 0.f;
        #pragma unroll
        for (int k = 0; k < NK; ++k)
            rv = fmaf(sWS[k], log2f(fmaxf(vk[k] * sCK[k], 1e-10f)), rv);
        if (sl == 0) sSel[row] = sMCq[row] * rv;
        __syncthreads();
        if (tid < 64) {
            float su = sSel[tid], ms = sMCq[tid];
            #pragma unroll
            for (int o = 32; o > 0; o >>= 1) {
                su += __shfl_xor(su, o, 64);
                ms += __shfl_xor(ms, o, 64);
            }
            if (tid == 0) dselPart[nq * 2 + qh] = make_float2(su, ms);
        }
    }
}

// ------- K3: softmax over q + denoise (float4-across-h, q-split-4) -----------
__global__ __launch_bounds__(256) void k_denoise(
    const float* __restrict__ hid, const float* __restrict__ attw,
    float* __restrict__ denoi)
{
    const int blk = blockIdx.x;          // nq*3 + chunk
    const int nq = blk / 3, ch = blk - nq * 3;
    const int tid = threadIdx.x, l = tid & 63, g = tid >> 6;
    __shared__ float sA[NE][LL];
    __shared__ f32x4 sP[4][NE][64];      // 20 KB partials
    for (int ep = g; ep < NE; ep += 4) {
        const float* ap = attw + ((size_t)ep * NN + nq) * LL;
        float a0 = ap[l], a1 = ap[l + 64];
        float m = fmaxf(a0, a1);
        #pragma unroll
        for (int o = 32; o > 0; o >>= 1) m = fmaxf(m, __shfl_xor(m, o, 64));
        float e0 = __expf(a0 - m), e1 = __expf(a1 - m);
        float s = e0 + e1;
        #pragma unroll
        for (int o = 32; o > 0; o >>= 1) s += __shfl_xor(s, o, 64);
        float inv = 1.0f / s;
        sA[ep][l] = e0 * inv;
        sA[ep][l + 64] = e1 * inv;
    }
    __syncthreads();
    const int h = ch * 256 + l * 4;
    const f32x4* hp = reinterpret_cast<const f32x4*>(hid + (size_t)nq * LL * HH + h);
    f32x4 p0 = {0,0,0,0}, p1 = {0,0,0,0}, p2 = {0,0,0,0}, p3 = {0,0,0,0}, p4 = {0,0,0,0};
    #pragma unroll 8
    for (int q = 0; q < 32; ++q) {
        const int qq = g * 32 + q;
        const f32x4 x = hp[(size_t)qq * (HH / 4)];
        p0 += sA[0][qq] * x;
        p1 += sA[1][qq] * x;
        p2 += sA[2][qq] * x;
        p3 += sA[3][qq] * x;
        p4 += sA[4][qq] * x;
    }
    sP[g][0][l] = p0; sP[g][1][l] = p1; sP[g][2][l] = p2;
    sP[g][3][l] = p3; sP[g][4][l] = p4;
    __syncthreads();
    if (tid < 64) {
        #define DNST(EP) { \
            f32x4 r = sP[0][EP][l] + sP[1][EP][l] + sP[2][EP][l] + sP[3][EP][l]; \
            *reinterpret_cast<f32x4*>(denoi + ((size_t)(EP) * NN + nq) * HH + h) = r; }
        DNST(0) DNST(1) DNST(2) DNST(3) DNST(4)
        #undef DNST
    }
}

// ---- K5b: GAT gate — float4, fully unrolled, one wave per (j-pair, 8 p's) ---
__global__ __launch_bounds__(256) void k_gat2(
    const float* __restrict__ inputs, const float* __restrict__ denoise,
    const float* __restrict__ w1t, const float* __restrict__ b1,
    const float* __restrict__ W2, float* __restrict__ part)
{
    const int wid = blockIdx.x * 4 + (threadIdx.x >> 6);
    const int l = threadIdx.x & 63;
    const int jp = wid & 63;
    const int po = wid >> 6;
    const int j0 = jp * 2, j1 = j0 + 1;
    const int pb = po * 8;

    const float4* wc0 = reinterpret_cast<const float4*>(w1t + (size_t)j0 * 1536) + l;
    const float4* wc1 = reinterpret_cast<const float4*>(w1t + (size_t)j1 * 1536) + l;
    const float4* fin[8]; const float4* fde[8];
    #pragma unroll
    for (int u = 0; u < 8; ++u) {
        const int p = pb + u;
        const int i = p / NN; const int n2 = p - i * NN; const int bb = n2 / NE;
        fin[u] = reinterpret_cast<const float4*>(inputs + ((size_t)bb * NE + i) * HH) + l;
        fde[u] = reinterpret_cast<const float4*>(denoise + (size_t)p * HH) + l;
    }
    float a0[8], a1[8];
    #pragma unroll
    for (int u = 0; u < 8; ++u) { a0[u] = 0.f; a1[u] = 0.f; }

    #pragma unroll
    for (int it = 0; it < 3; ++it) {
        const float4 w0v = wc0[it * 64], w1v = wc1[it * 64];
        #pragma unroll
        for (int u = 0; u < 8; ++u) {
            const float4 f = fin[u][it * 64];
            a0[u] += dot4(f, w0v);
            a1[u] += dot4(f, w1v);
        }
    }
    #pragma unroll
    for (int it = 0; it < 3; ++it) {
        const float4 w0v = wc0[192 + it * 64], w1v = wc1[192 + it * 64];
        #pragma unroll
        for (int u = 0; u < 8; ++u) {
            const float4 f = fde[u][it * 64];
            a0[u] += dot4(f, w0v);
            a1[u] += dot4(f, w1v);
        }
    }
    #pragma unroll
    for (int u = 0; u < 8; ++u) {
        #pragma unroll
        for (int o = 32; o > 0; o >>= 1) {
            a0[u] += __shfl_xor(a0[u], o, 64);
            a1[u] += __shfl_xor(a1[u], o, 64);
        }
    }
    const float bb0 = b1[j0], bb1 = b1[j1], w20 = W2[j0], w21 = W2[j1];
    if (l == 0) {
        #pragma unroll
        for (int u = 0; u < 8; ++u) {
            float v = fmaxf(a0[u] + bb0, 0.f) * w20 + fmaxf(a1[u] + bb1, 0.f) * w21;
            part[(size_t)(pb + u) * 64 + jp] = v;
        }
    }
}

// ---------------- K6a: per-(b,i) class logits (inlines gsc reduce) ----------
__global__ __launch_bounds__(256) void k_logits(
    const float* __restrict__ inputs, const float* __restrict__ denoise,
    const float* __restrict__ part, const float* __restrict__ inf_W,
    const float* __restrict__ inf_b, float* __restrict__ logi)
{
    const int bid = blockIdx.x;        // b*NE + i
    const int b = bid / NE, i = bid - b * NE;
    const int tid = threadIdx.x, l = tid & 63, wv = tid >> 6;
    __shared__ float sG[NE];
    for (int e2 = wv; e2 < NE; e2 += 4) {
        float v = part[(size_t)(i * NN + b * NE + e2) * 64 + l];
        #pragma unroll
        for (int o = 32; o > 0; o >>= 1) v += __shfl_xor(v, o, 64);
        if (l == 0) sG[e2] = v;
    }
    __syncthreads();
    float g0 = sG[0], g1 = sG[1], g2 = sG[2], g3 = sG[3], g4 = sG[4];
    float mm = fmaxf(fmaxf(fmaxf(g0, g1), fmaxf(g2, g3)), g4);
    float w0 = __expf(g0 - mm), w1 = __expf(g1 - mm), w2 = __expf(g2 - mm);
    float w3 = __expf(g3 - mm), w4 = __expf(g4 - mm);
    float inv = 1.0f / (w0 + w1 + w2 + w3 + w4);
    w0 *= inv; w1 *= inv; w2 *= inv; w3 *= inv; w4 *= inv;

    float p0 = 0.f, p1 = 0.f, p2 = 0.f;
    const float* xin = inputs + ((size_t)b * NE + i) * HH;
    const float* de = denoise + ((size_t)i * NN + b * NE) * HH;
    #pragma unroll
    for (int it = 0; it < 3; ++it) {
        int t = it * 256 + tid;
        float f = xin[t];
        p0 += f * inf_W[t * 3]; p1 += f * inf_W[t * 3 + 1]; p2 += f * inf_W[t * 3 + 2];
    }
    #pragma unroll
    for (int it = 0; it < 3; ++it) {
        int h = it * 256 + tid;
        float a = w0 * de[h] + w1 * de[HH + h] + w2 * de[2 * HH + h]
                + w3 * de[3 * HH + h] + w4 * de[4 * HH + h];
        int t = HH + h;
        p0 += a * inf_W[t * 3]; p1 += a * inf_W[t * 3 + 1]; p2 += a * inf_W[t * 3 + 2];
    }
    #pragma unroll
    for (int o = 32; o > 0; o >>= 1) {
        p0 += __shfl_xor(p0, o, 64);
        p1 += __shfl_xor(p1, o, 64);
        p2 += __shfl_xor(p2, o, 64);
    }
    __shared__ float red[4][NCLS];
    if (l == 0) { red[wv][0] = p0; red[wv][1] = p1; red[wv][2] = p2; }
    __syncthreads();
    if (tid < NCLS) {
        logi[bid * NCLS + tid] = red[0][tid] + red[1][tid] + red[2][tid] + red[3][tid]
                               + inf_b[tid];
    }
}

// ---------------- K6b: combine (finalizes dsel from partials) ---------------
__global__ __launch_bounds__(64) void k_combine(
    const float2* __restrict__ dselPart, const float* __restrict__ b_sel,
    const float* __restrict__ logi, float* __restrict__ out)
{
    const int b = threadIdx.x;
    if (b >= NB) return;
    const float bs = b_sel[0];
    float d0, d1, d2, d3, d4;
#define DSEL(I, D) { float2 pa = dselPart[(b * NE + (I)) * 2], pb = dselPart[(b * NE + (I)) * 2 + 1]; \
                     (D) = bs + 0.01f * (pa.x + pb.x) / ((pa.y + pb.y) + 1e-10f); }
    DSEL(0, d0) DSEL(1, d1) DSEL(2, d2) DSEL(3, d3) DSEL(4, d4)
#undef DSEL
    float m = fmaxf(fmaxf(fmaxf(d0, d1), fmaxf(d2, d3)), d4);
    float s0 = __expf(d0 - m), s1 = __expf(d1 - m), s2 = __expf(d2 - m);
    float s3 = __expf(d3 - m), s4 = __expf(d4 - m);
    float sinv = 1.0f / (s0 + s1 + s2 + s3 + s4);
    float sp0 = s0 * sinv, sp1 = s1 * sinv, sp2 = s2 * sinv, sp3 = s3 * sinv, sp4 = s4 * sinv;
    float acc0 = 0.f, acc1 = 0.f, acc2 = 0.f;
#define CMB(I, SP) { \
        float l0 = logi[(b * NE + (I)) * NCLS], l1 = logi[(b * NE + (I)) * NCLS + 1], \
              l2 = logi[(b * NE + (I)) * NCLS + 2]; \
        float mm = fmaxf(fmaxf(l0, l1), l2); \
        float e0 = __expf(l0 - mm), e1 = __expf(l1 - mm), e2 = __expf(l2 - mm); \
        float si = 1.0f / (e0 + e1 + e2); \
        acc0 += (SP) * e0 * si; acc1 += (SP) * e1 * si; acc2 += (SP) * e2 * si; }
    CMB(0, sp0) CMB(1, sp1) CMB(2, sp2) CMB(3, sp3) CMB(4, sp4)
#undef CMB
    out[b * NCLS + 0] = logf(acc0);
    out[b * NCLS + 1] = logf(acc1);
    out[b * NCLS + 2] = logf(acc2);
}

extern "C" void kernel_launch(void* const* d_in, const int* in_sizes, int n_in,
                              void* d_out, int out_size, void* d_ws, size_t ws_size,
                              hipStream_t stream) {
    (void)in_sizes; (void)n_in; (void)out_size; (void)ws_size;
    const float* hid           = (const float*)d_in[0];
    const float* inputs        = (const float*)d_in[1];
    const float* mask_text     = (const float*)d_in[2];
    const float* mask_claim    = (const float*)d_in[3];
    const float* mask_evidence = (const float*)d_in[4];
    const float* W_att  = (const float*)d_in[5];
    const float* b_att  = (const float*)d_in[6];
    const float* W_sel  = (const float*)d_in[7];
    const float* b_sel  = (const float*)d_in[8];
    const float* gat_W1 = (const float*)d_in[9];
    const float* gat_b1 = (const float*)d_in[10];
    const float* gat_W2 = (const float*)d_in[11];
    const float* gat_b2 = (const float*)d_in[12];
    const float* inf_W  = (const float*)d_in[13];
    const float* inf_b  = (const float*)d_in[14];
    (void)gat_b2;

    short* hswz  = (short*)d_ws;                              // 15,728,640 B
    float* denoi = (float*)((char*)d_ws + 15728640);          // 307,200 f
    float* attw  = denoi + 307200;                            // 51,200 f (raw logits)
    float2* dselPart = (float2*)(attw + 51200);               // 160 float2
    float* w1t   = (float*)(dselPart + 160);                  // 196,608 f
    float* part  = w1t + 196608;                              // 25,600 f
    float* logi  = part + 25600;                              // 240 f

    k_prep<<<688, 256, 0, stream>>>(hid, hswz, gat_W1, w1t);
    k_simpool<<<800, 256, 0, stream>>>(hswz, mask_text, mask_claim, mask_evidence,
                                       W_att, b_att, W_sel, attw, dselPart);
    k_denoise<<<NN * 3, 256, 0, stream>>>(hid, attw, denoi);
    k_gat2<<<800, 256, 0, stream>>>(inputs, denoi, w1t, gat_b1, gat_W2, part);
    k_logits<<<NN, 256, 0, stream>>>(inputs, denoi, part, inf_W, inf_b, logi);
    k_combine<<<1, 64, 0, stream>>>(dselPart, b_sel, logi, (float*)d_out);
}